// Round 5
// baseline (232.696 us; speedup 1.0000x reference)
//
#include <hip/hip_runtime.h>

// RelScaleAttend: b=4, 16 heads, s=1024 (32x32 img), d=64. Single fused kernel.
// Block = (h-pair, bh): 64 queries, 4 waves x 16 queries. K-tile = 32 keys.
// Static-max softmax (M = max_kh + max_kw bounds true row max within
// +-|qk|/8*log2e since every (kh,kw) occurs; shift cancels exactly).
// Raw lgkm-only barrier + LDS double-buffer + DISTANCE-2 register prefetch:
// tile kt+2 issued at top of iter kt, consumed at bottom of kt+1 (~2 iters of
// latency cover). LDS = exactly 40960 B -> 4 blocks/CU = whole grid resident.

#define SCALE2 0.18033688f   // 0.125 * log2(e)
#define LOG2E  1.44269504f

typedef float  f32x4  __attribute__((ext_vector_type(4)));
typedef __bf16 bf16x8 __attribute__((ext_vector_type(8)));
typedef __bf16 bf16x4 __attribute__((ext_vector_type(4)));
typedef __bf16 bf16x2 __attribute__((ext_vector_type(2)));

// Barrier waiting only on LDS ops (lgkmcnt(0)); global loads stay in flight.
// 0xC07F = vmcnt(63) expcnt(7) lgkmcnt(0).
__device__ __forceinline__ void ldsbar() {
    __asm__ volatile("" ::: "memory");
    __builtin_amdgcn_s_waitcnt(0xC07F);
    __builtin_amdgcn_s_barrier();
    __asm__ volatile("" ::: "memory");
}

__global__ __launch_bounds__(256, 4) void attn(
        const float* __restrict__ qg, const float* __restrict__ kg,
        const float* __restrict__ vg,
        const float* __restrict__ rph, const float* __restrict__ rpw,
        float* __restrict__ outg) {
    // LDS = 8448 + 8448 + 512 + 23552 = 40960 B exactly -> 4 blocks/CU.
    //   RelH/RelW 64x33 f32 (scalar access only; 33 = conflict-free writes)
    //   MH: 4x64 fp16 slot half-maxes (M precision irrelevant: shift cancels)
    //   arena: phase0 Ql 64x68 f32 (17408 B) / epilogue Ol (same) /
    //          phase1 Kb 2x(32x72) + Vb 2x(64x36) + Pl 4x(16x40) bf16
    __shared__ float RelH[64 * 33];
    __shared__ float RelW[64 * 33];
    __shared__ _Float16 MH[4 * 64];
    __shared__ __align__(16) __bf16 arena[11776];
    float*  Ql = (float*)arena;
    __bf16* Kb = arena;                 // 2 x 2304 el
    __bf16* Vb = arena + 4608;          // 2 x 2304 el
    __bf16* Pl = arena + 9216;          // 2560 el

    const int tid  = threadIdx.x;
    const int w    = tid >> 6, lane = tid & 63;
    const int quad = lane >> 4, n16 = lane & 15;
    const int hp = blockIdx.x, bh = blockIdx.y;
    const int bb = bh >> 4, nh = bh & 15;
    const int h0 = hp << 1;
    const int base = bb * 1048576 + nh * 64;   // per-head element base
    const int sq0  = h0 * 32;                  // first query row of block

    const int krow = tid >> 3, kc0 = (tid & 7) << 3;   // K staging coords
    const int vc = tid & 63, vk0 = (tid >> 6) << 3;    // V: d=vc, keys vk0..+7
    const int pw = w * 640;                            // per-wave P base

    // ---- issue tile 0 and tile 1 K/V loads immediately (2 reg sets) ----
    f32x4 kA0, kB0, kA1, kB1;
    float v0[8], v1[8];
    {
        const float* kp0 = kg + base + krow * 1024 + kc0;
        kA0 = ((const f32x4*)kp0)[0];
        kB0 = ((const f32x4*)kp0)[1];
        const float* vp0 = vg + base + vk0 * 1024 + vc;
#pragma unroll
        for (int j = 0; j < 8; ++j) v0[j] = vp0[j * 1024];
        const float* kp1 = kg + base + (32 + krow) * 1024 + kc0;
        kA1 = ((const f32x4*)kp1)[0];
        kB1 = ((const f32x4*)kp1)[1];
        const float* vp1 = vg + base + (32 + vk0) * 1024 + vc;
#pragma unroll
        for (int j = 0; j < 8; ++j) v1[j] = vp1[j * 1024];
    }

    // ---- stage Q rows (fp32) into LDS, coalesced b128 ----
    {
        int r0 = tid >> 4, c0 = (tid & 15) << 2;
#pragma unroll
        for (int k2 = 0; k2 < 4; ++k2) {
            int row = k2 * 16 + r0;
            *(f32x4*)&Ql[row * 68 + c0] =
                *(const f32x4*)(qg + base + (sq0 + row) * 1024 + c0);
        }
    }
    __syncthreads();

    // ---- phase 0: rel tables (x log2e) + per-slot half max ----
    {
        int ql = tid & 63, slot = tid >> 6;
        int isw = slot >> 1, khb = (slot & 1) << 4;
        int hh = h0 + (ql >> 5), wl = ql & 31;
        int row0 = (isw ? wl : hh) + 31 - khb;      // row_j = row0 - j
        const float* tp = (isw ? rpw : rph) + row0 * 64;
        const float* qrow = &Ql[ql * 68];
        float acc[16];
#pragma unroll
        for (int j = 0; j < 16; ++j) acc[j] = 0.f;
#pragma unroll 4
        for (int cq = 0; cq < 16; ++cq) {
            f32x4 qv = *(const f32x4*)(qrow + cq * 4);
#pragma unroll
            for (int j = 0; j < 16; ++j) {
                f32x4 tv = *(const f32x4*)(tp - j * 64 + cq * 4);
                acc[j] += qv.x * tv.x + qv.y * tv.y + qv.z * tv.z + qv.w * tv.w;
            }
        }
        float* dst = (isw ? RelW : RelH) + ql * 33 + khb;
        float hmax = -1e30f;
#pragma unroll
        for (int j = 0; j < 16; ++j) {
            float v = acc[j] * LOG2E;
            dst[j] = v;
            hmax = fmaxf(hmax, v);
        }
        MH[slot * 64 + ql] = (_Float16)hmax;
    }

    // ---- Q A-fragments from Ql: A[m=n16][k=quad*8+j], query = w*16+n16 ----
    const int qla = w * 16 + n16;
    bf16x8 qf[2];
#pragma unroll
    for (int ch = 0; ch < 2; ++ch) {
        const float* qp = &Ql[qla * 68 + ch * 32 + quad * 8];
        f32x4 a = ((const f32x4*)qp)[0];
        f32x4 b = ((const f32x4*)qp)[1];
        bf16x8 t;
        t[0] = (__bf16)a.x; t[1] = (__bf16)a.y; t[2] = (__bf16)a.z; t[3] = (__bf16)a.w;
        t[4] = (__bf16)b.x; t[5] = (__bf16)b.y; t[6] = (__bf16)b.z; t[7] = (__bf16)b.w;
        qf[ch] = t;
    }
    __syncthreads();   // Rel/MH ready; Ql dead -> arena becomes Kb/Vb/Pl

    // C/D rows this lane owns: local query = w*16 + quad*4 + r
    int qlr[4];
#pragma unroll
    for (int r = 0; r < 4; ++r) qlr[r] = w * 16 + quad * 4 + r;

    // per-row static max M and (rel_w - M); rel_w is tile-invariant
    float rwm[4][2];
#pragma unroll
    for (int r = 0; r < 4; ++r) {
        int q = qlr[r];
        float M = fmaxf((float)MH[q], (float)MH[64 + q])
                + fmaxf((float)MH[128 + q], (float)MH[192 + q]);
        rwm[r][0] = RelW[q * 33 + n16] - M;
        rwm[r][1] = RelW[q * 33 + 16 + n16] - M;
    }

    float lr[4] = {0.f, 0.f, 0.f, 0.f};
    f32x4 oc[4];
#pragma unroll
    for (int i = 0; i < 4; ++i) oc[i] = (f32x4){0.f, 0.f, 0.f, 0.f};

    // ---- staging helpers ----
    auto storeKV = [&](__bf16* Kd, __bf16* Vd, const f32x4& ka, const f32x4& kb2,
                       const float* vv) {
        bf16x8 t;
        t[0] = (__bf16)ka.x;  t[1] = (__bf16)ka.y;  t[2] = (__bf16)ka.z;  t[3] = (__bf16)ka.w;
        t[4] = (__bf16)kb2.x; t[5] = (__bf16)kb2.y; t[6] = (__bf16)kb2.z; t[7] = (__bf16)kb2.w;
        *(bf16x8*)&Kd[krow * 72 + kc0] = t;
#pragma unroll
        for (int j = 0; j < 4; ++j) {
            bf16x2 p; p[0] = (__bf16)vv[2 * j]; p[1] = (__bf16)vv[2 * j + 1];
            *(bf16x2*)&Vd[vc * 36 + vk0 + 2 * j] = p;
        }
    };
    auto loadKV = [&](int tile, f32x4& ka, f32x4& kb2, float* vv) {
        const float* kp = kg + base + (tile * 32 + krow) * 1024 + kc0;
        ka  = ((const f32x4*)kp)[0];
        kb2 = ((const f32x4*)kp)[1];
        const float* vp = vg + base + (tile * 32 + vk0) * 1024 + vc;
#pragma unroll
        for (int j = 0; j < 8; ++j) vv[j] = vp[j * 1024];
    };
    auto compute = [&](const __bf16* Kl, const __bf16* Vl, int kt) {
        float rh[4];
#pragma unroll
        for (int r = 0; r < 4; ++r) rh[r] = RelH[qlr[r] * 33 + kt];
        f32x4 s0 = {0.f, 0.f, 0.f, 0.f}, s1 = s0;
#pragma unroll
        for (int ch = 0; ch < 2; ++ch) {
            bf16x8 k0 = *(const bf16x8*)&Kl[n16 * 72 + ch * 32 + quad * 8];
            bf16x8 k1 = *(const bf16x8*)&Kl[(16 + n16) * 72 + ch * 32 + quad * 8];
            s0 = __builtin_amdgcn_mfma_f32_16x16x32_bf16(qf[ch], k0, s0, 0, 0, 0);
            s1 = __builtin_amdgcn_mfma_f32_16x16x32_bf16(qf[ch], k1, s1, 0, 0, 0);
        }
#pragma unroll
        for (int r = 0; r < 4; ++r) {
            float p0 = exp2f(fmaf(s0[r], SCALE2, rh[r] + rwm[r][0]));
            float p1 = exp2f(fmaf(s1[r], SCALE2, rh[r] + rwm[r][1]));
            lr[r] += p0 + p1;
            int pr = pw + (quad * 4 + r) * 40;
            Pl[pr + n16]      = (__bf16)p0;
            Pl[pr + 16 + n16] = (__bf16)p1;
        }
        bf16x8 pf = *(const bf16x8*)&Pl[pw + n16 * 40 + quad * 8];
#pragma unroll
        for (int cn = 0; cn < 4; ++cn) {
            const __bf16* vp2 = &Vl[(cn * 16 + n16) * 36 + quad * 8];
            bf16x4 a = *(const bf16x4*)vp2;
            bf16x4 b = *(const bf16x4*)(vp2 + 4);
            bf16x8 vf;
            vf[0] = a[0]; vf[1] = a[1]; vf[2] = a[2]; vf[3] = a[3];
            vf[4] = b[0]; vf[5] = b[1]; vf[6] = b[2]; vf[7] = b[3];
            oc[cn] = __builtin_amdgcn_mfma_f32_16x16x32_bf16(pf, vf, oc[cn], 0, 0, 0);
        }
    };

    // ---- software pipeline: store tile0, then 2-unrolled loop ----
    storeKV(Kb, Vb, kA0, kB0, v0);            // waits vmcnt for set0 only
    for (int kt = 0; kt < 32; kt += 2) {
        if (kt + 2 < 32) loadKV(kt + 2, kA0, kB0, v0);
        ldsbar();                              // buf0 visible; vmem in flight
        compute(Kb, Vb, kt);
        storeKV(Kb + 2304, Vb + 2304, kA1, kB1, v1);   // tile kt+1 -> buf1
        if (kt + 3 < 32) loadKV(kt + 3, kA1, kB1, v1);
        ldsbar();                              // buf1 visible
        compute(Kb + 2304, Vb + 2304, kt + 1);
        if (kt + 2 < 32) storeKV(Kb, Vb, kA0, kB0, v0);  // tile kt+2 -> buf0
    }

    // ---- epilogue: l-reduce, stage O rows in LDS, coalesced b128 stores ----
    float inv[4];
#pragma unroll
    for (int r = 0; r < 4; ++r) {
        float l = lr[r];
        l += __shfl_xor(l, 1);
        l += __shfl_xor(l, 2);
        l += __shfl_xor(l, 4);
        l += __shfl_xor(l, 8);
        inv[r] = 1.f / l;
    }
    __syncthreads();                 // arena reads done everywhere
    float* Ol = (float*)arena;       // 64 x 68 f32
#pragma unroll
    for (int r = 0; r < 4; ++r) {
        int row = w * 16 + quad * 4 + r;
        Ol[row * 68 + n16]      = oc[0][r] * inv[r];
        Ol[row * 68 + 16 + n16] = oc[1][r] * inv[r];
        Ol[row * 68 + 32 + n16] = oc[2][r] * inv[r];
        Ol[row * 68 + 48 + n16] = oc[3][r] * inv[r];
    }
    __syncthreads();
    {
        int rr = tid >> 4, cc = (tid & 15) << 2;
#pragma unroll
        for (int k2 = 0; k2 < 4; ++k2) {
            int row = k2 * 16 + rr;
            f32x4 val = *(const f32x4*)&Ol[row * 68 + cc];
            *(f32x4*)(outg + base + (sq0 + row) * 1024 + cc) = val;
        }
    }
}

extern "C" void kernel_launch(void* const* d_in, const int* in_sizes, int n_in,
                              void* d_out, int out_size, void* d_ws, size_t ws_size,
                              hipStream_t stream) {
    (void)in_sizes; (void)n_in; (void)out_size; (void)d_ws; (void)ws_size;
    const float* q   = (const float*)d_in[0];
    const float* k   = (const float*)d_in[1];
    const float* v   = (const float*)d_in[2];
    const float* rph = (const float*)d_in[3];
    const float* rpw = (const float*)d_in[4];
    dim3 g(16, 64);                      // (h-pair, bh)
    attn<<<g, 256, 0, stream>>>(q, k, v, rph, rpw, (float*)d_out);
}